// Round 1
// baseline (3083.977 us; speedup 1.0000x reference)
//
#include <hip/hip_runtime.h>
#include <math.h>

#define DH 128
#define NRBF 16

__device__ __forceinline__ float silu_f(float v) {
    return v / (1.f + __expf(-v));
}

// Detect whether edge_index arrived as int64 (little-endian: odd 32-bit words == 0
// since all indices < 50000) or as int32.
__global__ void k_detect(const int* __restrict__ ei, int* __restrict__ flag) {
    if (threadIdx.x == 0) {
        int z = 0;
#pragma unroll
        for (int i = 0; i < 8; ++i) z |= ei[2 * i + 1];
        *flag = (z == 0) ? 1 : 0;
    }
}

// ---------------------------------------------------------------------------
// Kernel 1: A = h @ Wm1[0:128,:] + bm1 ; B = h @ Wm1[128:256,:]
// 32 nodes/block, 256 threads, thread tile = 4 nodes x 8 cols (of 256 cols A|B)
// ---------------------------------------------------------------------------
__global__ __launch_bounds__(256) void k_precompute_ab(
    const float* __restrict__ h, const float* __restrict__ Wm1, const float* __restrict__ bm1,
    float* __restrict__ A, float* __restrict__ B, int N)
{
    __shared__ float sH[DH][36];      // h transposed [k][n], stride 36 (mult of 4)
    __shared__ float sW[16][256];     // weight k-tile: 16 rows x (A-half | B-half)
    const int tid = threadIdx.x;
    const int n0 = blockIdx.x * 32;

    {
        const int n = tid >> 3;
        const int c0 = (tid & 7) * 16;
        const int gn = n0 + n;
#pragma unroll
        for (int i = 0; i < 4; ++i) {
            float4 v = make_float4(0.f, 0.f, 0.f, 0.f);
            if (gn < N) v = *(const float4*)(h + (size_t)gn * DH + c0 + 4 * i);
            sH[c0 + 4 * i + 0][n] = v.x;
            sH[c0 + 4 * i + 1][n] = v.y;
            sH[c0 + 4 * i + 2][n] = v.z;
            sH[c0 + 4 * i + 3][n] = v.w;
        }
    }

    const int ng = tid & 7;           // node group (4 nodes)
    const int jg = tid >> 3;          // col group (8 cols of 256)
    const int sr = tid >> 4;          // staging row 0..15
    const int sc = (tid & 15) * 16;   // staging cols

    float acc[4][8];
#pragma unroll
    for (int i = 0; i < 4; ++i)
#pragma unroll
        for (int j = 0; j < 8; ++j) acc[i][j] = 0.f;

    float4 rw[4];
#pragma unroll
    for (int i = 0; i < 4; ++i) {
        const int c = sc + 4 * i;
        const float* p = (c < DH) ? (Wm1 + (size_t)sr * DH + c)
                                  : (Wm1 + (size_t)(DH + sr) * DH + (c - DH));
        rw[i] = *(const float4*)p;
    }

    for (int t = 0; t < 8; ++t) {
        __syncthreads();
#pragma unroll
        for (int i = 0; i < 4; ++i) *(float4*)&sW[sr][sc + 4 * i] = rw[i];
        __syncthreads();
        if (t < 7) {
            const int k0 = 16 * (t + 1);
#pragma unroll
            for (int i = 0; i < 4; ++i) {
                const int c = sc + 4 * i;
                const float* p = (c < DH) ? (Wm1 + (size_t)(k0 + sr) * DH + c)
                                          : (Wm1 + (size_t)(DH + k0 + sr) * DH + (c - DH));
                rw[i] = *(const float4*)p;
            }
        }
#pragma unroll
        for (int kk = 0; kk < 16; ++kk) {
            const float4 a  = *(const float4*)&sH[t * 16 + kk][ng * 4];
            const float4 b0 = *(const float4*)&sW[kk][jg * 8];
            const float4 b1 = *(const float4*)&sW[kk][jg * 8 + 4];
            const float av[4] = {a.x, a.y, a.z, a.w};
            const float bv[8] = {b0.x, b0.y, b0.z, b0.w, b1.x, b1.y, b1.z, b1.w};
#pragma unroll
            for (int i = 0; i < 4; ++i)
#pragma unroll
                for (int j = 0; j < 8; ++j)
                    acc[i][j] = fmaf(av[i], bv[j], acc[i][j]);
        }
    }

    const int j0 = jg * 8;
#pragma unroll
    for (int i = 0; i < 4; ++i) {
        const int gn = n0 + ng * 4 + i;
        if (gn >= N) continue;
        if (j0 < DH) {
            float o[8];
#pragma unroll
            for (int j = 0; j < 8; ++j) o[j] = acc[i][j] + bm1[j0 + j];
            *(float4*)(A + (size_t)gn * DH + j0)     = make_float4(o[0], o[1], o[2], o[3]);
            *(float4*)(A + (size_t)gn * DH + j0 + 4) = make_float4(o[4], o[5], o[6], o[7]);
        } else {
            const int jb = j0 - DH;
            *(float4*)(B + (size_t)gn * DH + jb)     = make_float4(acc[i][0], acc[i][1], acc[i][2], acc[i][3]);
            *(float4*)(B + (size_t)gn * DH + jb + 4) = make_float4(acc[i][4], acc[i][5], acc[i][6], acc[i][7]);
        }
    }
}

// ---------------------------------------------------------------------------
// Kernel 2: per edge  hidden = silu(A[src] + B[dst] + rbf@Wm1[256:272])
//           m = (hidden @ Wm2 + bm2) * ew ;  atomicAdd into agg[dst]
// 128 edges/block, 512 threads. GEMM thread tile = 4 edges x 8 cols.
// ---------------------------------------------------------------------------
__global__ __launch_bounds__(512) void k_edge(
    const float* __restrict__ x, const int* __restrict__ ei, const float* __restrict__ ew,
    const float* __restrict__ Wm1, const float* __restrict__ Wm2, const float* __restrict__ bm2,
    const float* __restrict__ A, const float* __restrict__ B,
    float* __restrict__ agg, const int* __restrict__ flag, int N, int E)
{
    __shared__ float sHid[DH][132];   // hidden transposed [k][e], stride 132
    __shared__ float sW2[DH][DH];     // full Wm2
    __shared__ float sW1c[NRBF][DH];  // Wm1 rows 256..271
    __shared__ int   sSrc[128];
    __shared__ int   sDst[128];
    __shared__ float sEw[128];

    const int tid = threadIdx.x;
    const int e0 = blockIdx.x * 128;

    {
        const float4* s4 = (const float4*)Wm2;
        float4* d4 = (float4*)&sW2[0][0];
#pragma unroll
        for (int i = 0; i < 8; ++i) d4[tid + 512 * i] = s4[tid + 512 * i];
        ((float4*)&sW1c[0][0])[tid] = ((const float4*)(Wm1 + 256 * DH))[tid];
    }
    if (tid < 128) {
        const int eg = e0 + tid;
        int s = 0, d = 0;
        float w = 0.f;
        if (eg < E) {
            if (*flag) { s = ei[2 * eg]; d = ei[2 * E + 2 * eg]; }
            else       { s = ei[eg];     d = ei[E + eg]; }
            w = ew[eg];
        }
        sSrc[tid] = s; sDst[tid] = d; sEw[tid] = w;
    }
    __syncthreads();

    // build hidden (4 threads/edge, interleaved 4-col chunks to dodge bank conflicts)
    {
        const int e  = tid >> 2;
        const int cb = (tid & 3) * 4;
        const int s = sSrc[e], d = sDst[e];
        const float2 xs = *(const float2*)(x + 2 * s);
        const float2 xd = *(const float2*)(x + 2 * d);
        const float dxv = xs.x - xd.x, dyv = xs.y - xd.y;
        const float r = sqrtf(dxv * dxv + dyv * dyv + 1e-8f);
        const float WIDTH = 0.09428090415820634f;  // sqrt(2)/15
        const float GAMMA = 56.25f;                // 1/(2*WIDTH^2)
        float rb[NRBF];
#pragma unroll
        for (int q = 0; q < NRBF; ++q) {
            const float t = r - (float)q * WIDTH;
            rb[q] = __expf(-GAMMA * t * t);
        }
        float4 hv[8];
#pragma unroll
        for (int i = 0; i < 8; ++i) {
            const float4 a4 = *(const float4*)(A + (size_t)s * DH + cb + 16 * i);
            const float4 b4 = *(const float4*)(B + (size_t)d * DH + cb + 16 * i);
            hv[i] = make_float4(a4.x + b4.x, a4.y + b4.y, a4.z + b4.z, a4.w + b4.w);
        }
#pragma unroll
        for (int q = 0; q < NRBF; ++q) {
            const float rq = rb[q];
#pragma unroll
            for (int i = 0; i < 8; ++i) {
                const float4 w4 = *(const float4*)&sW1c[q][cb + 16 * i];
                hv[i].x = fmaf(rq, w4.x, hv[i].x);
                hv[i].y = fmaf(rq, w4.y, hv[i].y);
                hv[i].z = fmaf(rq, w4.z, hv[i].z);
                hv[i].w = fmaf(rq, w4.w, hv[i].w);
            }
        }
#pragma unroll
        for (int i = 0; i < 8; ++i) {
            const int c = cb + 16 * i;
            sHid[c + 0][e] = silu_f(hv[i].x);
            sHid[c + 1][e] = silu_f(hv[i].y);
            sHid[c + 2][e] = silu_f(hv[i].z);
            sHid[c + 3][e] = silu_f(hv[i].w);
        }
    }
    __syncthreads();

    // GEMM2: m[e][j] = sum_k hid[k][e] * Wm2[k][j]
    {
        const int jg = tid & 15, eg = tid >> 4;
        const int j0 = jg * 8, eb = eg * 4;
        float acc[4][8];
#pragma unroll
        for (int i = 0; i < 4; ++i)
#pragma unroll
            for (int j = 0; j < 8; ++j) acc[i][j] = 0.f;

#pragma unroll 4
        for (int k = 0; k < DH; ++k) {
            const float4 a  = *(const float4*)&sHid[k][eb];
            const float4 b0 = *(const float4*)&sW2[k][j0];
            const float4 b1 = *(const float4*)&sW2[k][j0 + 4];
            const float av[4] = {a.x, a.y, a.z, a.w};
            const float bv[8] = {b0.x, b0.y, b0.z, b0.w, b1.x, b1.y, b1.z, b1.w};
#pragma unroll
            for (int i = 0; i < 4; ++i)
#pragma unroll
                for (int j = 0; j < 8; ++j)
                    acc[i][j] = fmaf(av[i], bv[j], acc[i][j]);
        }
        float bias[8];
#pragma unroll
        for (int j = 0; j < 8; ++j) bias[j] = bm2[j0 + j];
#pragma unroll
        for (int i = 0; i < 4; ++i) {
            const int e = eb + i;
            if (e0 + e < E) {
                const float w = sEw[e];
                float* dst = agg + (size_t)sDst[e] * DH + j0;
#pragma unroll
                for (int j = 0; j < 8; ++j)
                    atomicAdd(dst + j, (acc[i][j] + bias[j]) * w);
            }
        }
    }
}

// ---------------------------------------------------------------------------
// Kernel 3: node MLP + residual + LayerNorm. 32 nodes/block, 256 threads.
// ---------------------------------------------------------------------------
__global__ __launch_bounds__(256) void k_node(
    const float* __restrict__ h, const float* __restrict__ agg,
    const float* __restrict__ Wh1, const float* __restrict__ bh1,
    const float* __restrict__ Wh2, const float* __restrict__ bh2,
    const float* __restrict__ ln_g, const float* __restrict__ ln_b,
    float* __restrict__ out, int N)
{
    __shared__ float sU[2 * DH][36];  // u_in transposed [k][n]; later reused for z
    __shared__ float sHid[DH][36];
    __shared__ float sW[16][DH];
    __shared__ float sMean[32], sRstd[32];
    const int tid = threadIdx.x;
    const int n0 = blockIdx.x * 32;

    {
        const int n = tid >> 3;
        const int c0 = (tid & 7) * 16;
        const int gn = n0 + n;
#pragma unroll
        for (int i = 0; i < 4; ++i) {
            float4 v = make_float4(0.f, 0.f, 0.f, 0.f);
            if (gn < N) v = *(const float4*)(h + (size_t)gn * DH + c0 + 4 * i);
            sU[c0 + 4 * i + 0][n] = v.x; sU[c0 + 4 * i + 1][n] = v.y;
            sU[c0 + 4 * i + 2][n] = v.z; sU[c0 + 4 * i + 3][n] = v.w;
        }
#pragma unroll
        for (int i = 0; i < 4; ++i) {
            float4 v = make_float4(0.f, 0.f, 0.f, 0.f);
            if (gn < N) v = *(const float4*)(agg + (size_t)gn * DH + c0 + 4 * i);
            sU[DH + c0 + 4 * i + 0][n] = v.x; sU[DH + c0 + 4 * i + 1][n] = v.y;
            sU[DH + c0 + 4 * i + 2][n] = v.z; sU[DH + c0 + 4 * i + 3][n] = v.w;
        }
    }

    const int ng = tid & 7;           // 4 nodes
    const int jg = tid >> 3;          // 4 cols
    const int sr = tid >> 4;
    const int sc = (tid & 15) * 8;

    float acc[4][4];
#pragma unroll
    for (int i = 0; i < 4; ++i)
#pragma unroll
        for (int j = 0; j < 4; ++j) acc[i][j] = 0.f;

    float4 rw[2];
    rw[0] = *(const float4*)(Wh1 + (size_t)sr * DH + sc);
    rw[1] = *(const float4*)(Wh1 + (size_t)sr * DH + sc + 4);
    for (int t = 0; t < 16; ++t) {
        __syncthreads();
        *(float4*)&sW[sr][sc]     = rw[0];
        *(float4*)&sW[sr][sc + 4] = rw[1];
        __syncthreads();
        if (t < 15) {
            const int k0 = 16 * (t + 1);
            rw[0] = *(const float4*)(Wh1 + (size_t)(k0 + sr) * DH + sc);
            rw[1] = *(const float4*)(Wh1 + (size_t)(k0 + sr) * DH + sc + 4);
        }
#pragma unroll
        for (int kk = 0; kk < 16; ++kk) {
            const float4 a = *(const float4*)&sU[t * 16 + kk][ng * 4];
            const float4 b = *(const float4*)&sW[kk][jg * 4];
            const float av[4] = {a.x, a.y, a.z, a.w};
            const float bv[4] = {b.x, b.y, b.z, b.w};
#pragma unroll
            for (int i = 0; i < 4; ++i)
#pragma unroll
                for (int j = 0; j < 4; ++j)
                    acc[i][j] = fmaf(av[i], bv[j], acc[i][j]);
        }
    }
    // silu + bias -> sHid transposed
#pragma unroll
    for (int jj = 0; jj < 4; ++jj) {
        const float bb = bh1[jg * 4 + jj];
#pragma unroll
        for (int i = 0; i < 4; ++i)
            sHid[jg * 4 + jj][ng * 4 + i] = silu_f(acc[i][jj] + bb);
    }

    float acc2[4][4];
#pragma unroll
    for (int i = 0; i < 4; ++i)
#pragma unroll
        for (int j = 0; j < 4; ++j) acc2[i][j] = 0.f;

    rw[0] = *(const float4*)(Wh2 + (size_t)sr * DH + sc);
    rw[1] = *(const float4*)(Wh2 + (size_t)sr * DH + sc + 4);
    for (int t = 0; t < 8; ++t) {
        __syncthreads();
        *(float4*)&sW[sr][sc]     = rw[0];
        *(float4*)&sW[sr][sc + 4] = rw[1];
        __syncthreads();
        if (t < 7) {
            const int k0 = 16 * (t + 1);
            rw[0] = *(const float4*)(Wh2 + (size_t)(k0 + sr) * DH + sc);
            rw[1] = *(const float4*)(Wh2 + (size_t)(k0 + sr) * DH + sc + 4);
        }
#pragma unroll
        for (int kk = 0; kk < 16; ++kk) {
            const float4 a = *(const float4*)&sHid[t * 16 + kk][ng * 4];
            const float4 b = *(const float4*)&sW[kk][jg * 4];
            const float av[4] = {a.x, a.y, a.z, a.w};
            const float bv[4] = {b.x, b.y, b.z, b.w};
#pragma unroll
            for (int i = 0; i < 4; ++i)
#pragma unroll
                for (int j = 0; j < 4; ++j)
                    acc2[i][j] = fmaf(av[i], bv[j], acc2[i][j]);
        }
    }

    // z = h + h_up -> store transposed into sU (rows 0..127)
#pragma unroll
    for (int jj = 0; jj < 4; ++jj) {
        const float bb = bh2[jg * 4 + jj];
#pragma unroll
        for (int i = 0; i < 4; ++i) {
            const int gn = n0 + ng * 4 + i;
            float hv = 0.f;
            if (gn < N) hv = h[(size_t)gn * DH + jg * 4 + jj];
            sU[jg * 4 + jj][ng * 4 + i] = acc2[i][jj] + bb + hv;
        }
    }
    __syncthreads();

    // LayerNorm: 8 threads per node, strided partials + shfl reduce
    {
        const int n = tid >> 3, sub = tid & 7;
        float s1 = 0.f, s2 = 0.f;
#pragma unroll
        for (int i = 0; i < 16; ++i) {
            const float z = sU[sub + 8 * i][n];
            s1 += z; s2 += z * z;
        }
#pragma unroll
        for (int m = 1; m < 8; m <<= 1) {
            s1 += __shfl_xor(s1, m, 64);
            s2 += __shfl_xor(s2, m, 64);
        }
        if (sub == 0) {
            const float mean = s1 * (1.f / 128.f);
            const float var = s2 * (1.f / 128.f) - mean * mean;
            sMean[n] = mean;
            sRstd[n] = rsqrtf(var + 1e-5f);
        }
    }
    __syncthreads();
    {
        const int n = tid >> 3, c0 = (tid & 7) * 16;
        const int gn = n0 + n;
        if (gn < N) {
            const float mean = sMean[n], rstd = sRstd[n];
#pragma unroll
            for (int i = 0; i < 4; ++i) {
                const float4 g4 = *(const float4*)(ln_g + c0 + 4 * i);
                const float4 b4 = *(const float4*)(ln_b + c0 + 4 * i);
                float4 o;
                o.x = (sU[c0 + 4 * i + 0][n] - mean) * rstd * g4.x + b4.x;
                o.y = (sU[c0 + 4 * i + 1][n] - mean) * rstd * g4.y + b4.y;
                o.z = (sU[c0 + 4 * i + 2][n] - mean) * rstd * g4.z + b4.z;
                o.w = (sU[c0 + 4 * i + 3][n] - mean) * rstd * g4.w + b4.w;
                *(float4*)(out + (size_t)gn * DH + c0 + 4 * i) = o;
            }
        }
    }
}

extern "C" void kernel_launch(void* const* d_in, const int* in_sizes, int n_in,
                              void* d_out, int out_size, void* d_ws, size_t ws_size,
                              hipStream_t stream)
{
    (void)n_in; (void)out_size; (void)ws_size;
    const float* h   = (const float*)d_in[0];
    const float* x   = (const float*)d_in[1];
    const int*   ei  = (const int*)d_in[2];
    const float* ew  = (const float*)d_in[3];
    const float* Wm1 = (const float*)d_in[4];
    const float* bm1 = (const float*)d_in[5];
    const float* Wm2 = (const float*)d_in[6];
    const float* bm2 = (const float*)d_in[7];
    const float* Wh1 = (const float*)d_in[8];
    const float* bh1 = (const float*)d_in[9];
    const float* Wh2 = (const float*)d_in[10];
    const float* bh2 = (const float*)d_in[11];
    const float* lng = (const float*)d_in[12];
    const float* lnb = (const float*)d_in[13];
    float* out = (float*)d_out;

    const int N = in_sizes[0] / DH;
    const int E = in_sizes[3];

    float* agg = (float*)d_ws;
    float* A   = agg + (size_t)N * DH;
    float* B   = A + (size_t)N * DH;
    int* flag  = (int*)(B + (size_t)N * DH);

    hipMemsetAsync(agg, 0, (size_t)N * DH * sizeof(float), stream);
    k_detect<<<1, 64, 0, stream>>>(ei, flag);
    k_precompute_ab<<<(N + 31) / 32, 256, 0, stream>>>(h, Wm1, bm1, A, B, N);
    k_edge<<<(E + 127) / 128, 512, 0, stream>>>(x, ei, ew, Wm1, Wm2, bm2, A, B, agg, flag, N, E);
    k_node<<<(N + 31) / 32, 256, 0, stream>>>(h, agg, Wh1, bh1, Wh2, bh2, lng, lnb, out, N);
}

// Round 2
// 743.450 us; speedup vs baseline: 4.1482x; 4.1482x over previous
//
#include <hip/hip_runtime.h>
#include <math.h>

#define DH 128
#define NRBF 16
#define EB 128   // edges per k_edge block

typedef __attribute__((ext_vector_type(8))) short short8;
typedef __attribute__((ext_vector_type(4))) float floatx4;

__device__ __forceinline__ float silu_f(float v) {
    return v / (1.f + __expf(-v));
}

__device__ __forceinline__ unsigned short f2bf(float f) {
    unsigned int u = __float_as_uint(f);
    u += 0x7FFFu + ((u >> 16) & 1u);   // RNE
    return (unsigned short)(u >> 16);
}

// Detect whether edge_index arrived as int64 (odd 32-bit words all zero) or int32.
__global__ void k_detect(const int* __restrict__ ei, int* __restrict__ flag) {
    if (threadIdx.x == 0) {
        int z = 0;
#pragma unroll
        for (int i = 0; i < 8; ++i) z |= ei[2 * i + 1];
        *flag = (z == 0) ? 1 : 0;
    }
}

__device__ __forceinline__ int load_dst(const int* ei, int is64, int e, int E) {
    return is64 ? ei[2 * E + 2 * e] : ei[E + e];
}
__device__ __forceinline__ int load_src(const int* ei, int is64, int e, int E) {
    return is64 ? ei[2 * e] : ei[e];
}

// ---------------- counting sort by dst ----------------
__global__ void k_hist(const int* __restrict__ ei, const int* __restrict__ flag,
                       int* __restrict__ counts, int E) {
    const int e = blockIdx.x * 256 + threadIdx.x;
    if (e < E) atomicAdd(&counts[load_dst(ei, *flag, e, E)], 1);
}

__global__ __launch_bounds__(1024) void k_scan(const int* __restrict__ counts,
                                               int* __restrict__ cursor, int N) {
    __shared__ int wsum[16];
    __shared__ int sCarry;
    const int tid = threadIdx.x, lane = tid & 63, wid = tid >> 6;
    if (tid == 0) sCarry = 0;
    __syncthreads();
    for (int c0 = 0; c0 < N; c0 += 1024) {
        const int i = c0 + tid;
        const int v = (i < N) ? counts[i] : 0;
        int incl = v;
#pragma unroll
        for (int d = 1; d < 64; d <<= 1) {
            int t = __shfl_up(incl, d, 64);
            if (lane >= d) incl += t;
        }
        if (lane == 63) wsum[wid] = incl;
        __syncthreads();
        if (wid == 0) {
            int s = (lane < 16) ? wsum[lane] : 0;
#pragma unroll
            for (int d = 1; d < 16; d <<= 1) {
                int t = __shfl_up(s, d, 64);
                if (lane >= d) s += t;
            }
            if (lane < 16) wsum[lane] = s;
        }
        __syncthreads();
        const int base = sCarry + (wid > 0 ? wsum[wid - 1] : 0);
        if (i < N) cursor[i] = base + incl - v;   // exclusive prefix
        __syncthreads();
        if (tid == 0) sCarry += wsum[15];
        __syncthreads();
    }
}

__global__ void k_scatter(const int* __restrict__ ei, const int* __restrict__ flag,
                          int* __restrict__ cursor, int* __restrict__ perm, int E) {
    const int e = blockIdx.x * 256 + threadIdx.x;
    if (e < E) {
        const int d = load_dst(ei, *flag, e, E);
        const int pos = atomicAdd(&cursor[d], 1);
        perm[pos] = e;
    }
}

// ---------------------------------------------------------------------------
// Kernel 1: A = h @ Wm1[0:128,:] + bm1 ; B = h @ Wm1[128:256,:]  (fp32)
// ---------------------------------------------------------------------------
__global__ __launch_bounds__(256) void k_precompute_ab(
    const float* __restrict__ h, const float* __restrict__ Wm1, const float* __restrict__ bm1,
    float* __restrict__ A, float* __restrict__ B, int N)
{
    __shared__ float sH[DH][36];
    __shared__ float sW[16][256];
    const int tid = threadIdx.x;
    const int n0 = blockIdx.x * 32;

    {
        const int n = tid >> 3;
        const int c0 = (tid & 7) * 16;
        const int gn = n0 + n;
#pragma unroll
        for (int i = 0; i < 4; ++i) {
            float4 v = make_float4(0.f, 0.f, 0.f, 0.f);
            if (gn < N) v = *(const float4*)(h + (size_t)gn * DH + c0 + 4 * i);
            sH[c0 + 4 * i + 0][n] = v.x;
            sH[c0 + 4 * i + 1][n] = v.y;
            sH[c0 + 4 * i + 2][n] = v.z;
            sH[c0 + 4 * i + 3][n] = v.w;
        }
    }

    const int ng = tid & 7;
    const int jg = tid >> 3;
    const int sr = tid >> 4;
    const int sc = (tid & 15) * 16;

    float acc[4][8];
#pragma unroll
    for (int i = 0; i < 4; ++i)
#pragma unroll
        for (int j = 0; j < 8; ++j) acc[i][j] = 0.f;

    float4 rw[4];
#pragma unroll
    for (int i = 0; i < 4; ++i) {
        const int c = sc + 4 * i;
        const float* p = (c < DH) ? (Wm1 + (size_t)sr * DH + c)
                                  : (Wm1 + (size_t)(DH + sr) * DH + (c - DH));
        rw[i] = *(const float4*)p;
    }

    for (int t = 0; t < 8; ++t) {
        __syncthreads();
#pragma unroll
        for (int i = 0; i < 4; ++i) *(float4*)&sW[sr][sc + 4 * i] = rw[i];
        __syncthreads();
        if (t < 7) {
            const int k0 = 16 * (t + 1);
#pragma unroll
            for (int i = 0; i < 4; ++i) {
                const int c = sc + 4 * i;
                const float* p = (c < DH) ? (Wm1 + (size_t)(k0 + sr) * DH + c)
                                          : (Wm1 + (size_t)(DH + k0 + sr) * DH + (c - DH));
                rw[i] = *(const float4*)p;
            }
        }
#pragma unroll
        for (int kk = 0; kk < 16; ++kk) {
            const float4 a  = *(const float4*)&sH[t * 16 + kk][ng * 4];
            const float4 b0 = *(const float4*)&sW[kk][jg * 8];
            const float4 b1 = *(const float4*)&sW[kk][jg * 8 + 4];
            const float av[4] = {a.x, a.y, a.z, a.w};
            const float bv[8] = {b0.x, b0.y, b0.z, b0.w, b1.x, b1.y, b1.z, b1.w};
#pragma unroll
            for (int i = 0; i < 4; ++i)
#pragma unroll
                for (int j = 0; j < 8; ++j)
                    acc[i][j] = fmaf(av[i], bv[j], acc[i][j]);
        }
    }

    const int j0 = jg * 8;
#pragma unroll
    for (int i = 0; i < 4; ++i) {
        const int gn = n0 + ng * 4 + i;
        if (gn >= N) continue;
        if (j0 < DH) {
            float o[8];
#pragma unroll
            for (int j = 0; j < 8; ++j) o[j] = acc[i][j] + bm1[j0 + j];
            *(float4*)(A + (size_t)gn * DH + j0)     = make_float4(o[0], o[1], o[2], o[3]);
            *(float4*)(A + (size_t)gn * DH + j0 + 4) = make_float4(o[4], o[5], o[6], o[7]);
        } else {
            const int jb = j0 - DH;
            *(float4*)(B + (size_t)gn * DH + jb)     = make_float4(acc[i][0], acc[i][1], acc[i][2], acc[i][3]);
            *(float4*)(B + (size_t)gn * DH + jb + 4) = make_float4(acc[i][4], acc[i][5], acc[i][6], acc[i][7]);
        }
    }
}

// ---------------------------------------------------------------------------
// Kernel 2: per (sorted) edge  hidden = silu(A[src]+B[dst]+rbf@Wm1c)  [bf16]
//           m = (hidden @ Wm2 + bm2) * ew  via MFMA ;  merged atomicAdd agg
// 128 edges/block, 256 threads (4 waves). Each wave: 32 edges x 128 cols.
// ---------------------------------------------------------------------------
__global__ __launch_bounds__(256, 2) void k_edge(
    const float* __restrict__ x, const int* __restrict__ ei, const float* __restrict__ ew,
    const float* __restrict__ Wm1, const float* __restrict__ Wm2, const float* __restrict__ bm2,
    const float* __restrict__ A, const float* __restrict__ B,
    float* __restrict__ agg, const int* __restrict__ flag,
    const int* __restrict__ perm, int use_perm, int N, int E)
{
    __shared__ unsigned short sHid[EB][136];   // hidden bf16 [edge][k], stride 136 (16B aligned rows)
    __shared__ unsigned short sW2t[DH][132];   // Wm2 transposed bf16 [col][k]
    __shared__ float sW1c[NRBF][DH];           // Wm1 rows 256..271 (rbf part)
    __shared__ int   sSrc[EB];
    __shared__ int   sDst[EB];
    __shared__ float sEw[EB];

    const int tid = threadIdx.x;
    const int e0 = blockIdx.x * EB;

    // stage rbf weight rows (fp32)
    {
        const float4* s4 = (const float4*)(Wm1 + 256 * DH);
        float4* d4 = (float4*)&sW1c[0][0];
        d4[tid] = s4[tid];
        d4[tid + 256] = s4[tid + 256];
    }
    // stage Wm2 transposed as bf16
#pragma unroll
    for (int i = 0; i < 16; ++i) {
        const int idx = i * 1024 + tid * 4;
        const int k = idx >> 7, j = idx & 127;
        const float4 v = *(const float4*)(Wm2 + idx);
        sW2t[j + 0][k] = f2bf(v.x);
        sW2t[j + 1][k] = f2bf(v.y);
        sW2t[j + 2][k] = f2bf(v.z);
        sW2t[j + 3][k] = f2bf(v.w);
    }
    if (tid < EB) {
        const int slot = e0 + tid;
        int s = 0, d = 0;
        float w = 0.f;
        if (slot < E) {
            const int e = use_perm ? perm[slot] : slot;
            const int is64 = *flag;
            s = load_src(ei, is64, e, E);
            d = load_dst(ei, is64, e, E);
            w = ew[e];
        }
        sSrc[tid] = s; sDst[tid] = d; sEw[tid] = w;
    }
    __syncthreads();

    // phase 1: build hidden (2 threads/edge, 64 cols each), silu, bf16 -> LDS
    {
        const int e  = tid >> 1;
        const int c0 = (tid & 1) * 64;
        const int s = sSrc[e], d = sDst[e];
        const float2 xs = *(const float2*)(x + 2 * s);
        const float2 xd = *(const float2*)(x + 2 * d);
        const float dxv = xs.x - xd.x, dyv = xs.y - xd.y;
        const float r = sqrtf(dxv * dxv + dyv * dyv + 1e-8f);
        const float WIDTH = 0.09428090415820634f;  // sqrt(2)/15
        const float GAMMA = 56.25f;                // 1/(2*WIDTH^2)
        float rb[NRBF];
#pragma unroll
        for (int q = 0; q < NRBF; ++q) {
            const float t = r - (float)q * WIDTH;
            rb[q] = __expf(-GAMMA * t * t);
        }
        float4 hv[16];
#pragma unroll
        for (int i = 0; i < 16; ++i) {
            const float4 a4 = *(const float4*)(A + (size_t)s * DH + c0 + 4 * i);
            const float4 b4 = *(const float4*)(B + (size_t)d * DH + c0 + 4 * i);
            hv[i] = make_float4(a4.x + b4.x, a4.y + b4.y, a4.z + b4.z, a4.w + b4.w);
        }
#pragma unroll
        for (int q = 0; q < NRBF; ++q) {
            const float rq = rb[q];
#pragma unroll
            for (int i = 0; i < 16; ++i) {
                const float4 w4 = *(const float4*)&sW1c[q][c0 + 4 * i];
                hv[i].x = fmaf(rq, w4.x, hv[i].x);
                hv[i].y = fmaf(rq, w4.y, hv[i].y);
                hv[i].z = fmaf(rq, w4.z, hv[i].z);
                hv[i].w = fmaf(rq, w4.w, hv[i].w);
            }
        }
#pragma unroll
        for (int i = 0; i < 8; ++i) {
            const float4 a = hv[2 * i];
            const float4 b = hv[2 * i + 1];
            uint4 pk;
            pk.x = (unsigned)f2bf(silu_f(a.x)) | ((unsigned)f2bf(silu_f(a.y)) << 16);
            pk.y = (unsigned)f2bf(silu_f(a.z)) | ((unsigned)f2bf(silu_f(a.w)) << 16);
            pk.z = (unsigned)f2bf(silu_f(b.x)) | ((unsigned)f2bf(silu_f(b.y)) << 16);
            pk.w = (unsigned)f2bf(silu_f(b.z)) | ((unsigned)f2bf(silu_f(b.w)) << 16);
            *(uint4*)&sHid[e][c0 + 8 * i] = pk;
        }
    }
    __syncthreads();

    // phase 2: MFMA GEMM2  C[128e][128j] = hid @ Wm2
    const int lane = tid & 63;
    const int wv   = tid >> 6;
    const int m0   = wv * 32;
    const int lr   = lane & 15;   // row/col within 16
    const int lg   = lane >> 4;   // k-group 0..3

    floatx4 acc[2][8];
#pragma unroll
    for (int mi = 0; mi < 2; ++mi)
#pragma unroll
        for (int ni = 0; ni < 8; ++ni) acc[mi][ni] = (floatx4){0.f, 0.f, 0.f, 0.f};

    union FragU { uint2 u2[2]; short8 s8; };

#pragma unroll
    for (int kc = 0; kc < 4; ++kc) {
        const int kb = kc * 32 + 4 * lg;
        FragU af[2];
#pragma unroll
        for (int mi = 0; mi < 2; ++mi) {
            const unsigned short* p = &sHid[m0 + mi * 16 + lr][kb];
            af[mi].u2[0] = *(const uint2*)p;
            af[mi].u2[1] = *(const uint2*)(p + 16);
        }
#pragma unroll
        for (int ni = 0; ni < 8; ++ni) {
            const unsigned short* q = &sW2t[ni * 16 + lr][kb];
            FragU bf;
            bf.u2[0] = *(const uint2*)q;
            bf.u2[1] = *(const uint2*)(q + 16);
            acc[0][ni] = __builtin_amdgcn_mfma_f32_16x16x32_bf16(af[0].s8, bf.s8, acc[0][ni], 0, 0, 0);
            acc[1][ni] = __builtin_amdgcn_mfma_f32_16x16x32_bf16(af[1].s8, bf.s8, acc[1][ni], 0, 0, 0);
        }
    }

    // phase 3: bias, edge-weight, run-merged atomic scatter
    // C layout: col = ni*16 + lr ; edge slot = m0 + mi*16 + 4*lg + r
#pragma unroll
    for (int ni = 0; ni < 8; ++ni) {
        const int col = ni * 16 + lr;
        const float bc = bm2[col];
#pragma unroll
        for (int mi = 0; mi < 2; ++mi) {
            const int sbase = m0 + mi * 16 + 4 * lg;
            int cur = sDst[sbase];
            float av = (acc[mi][ni][0] + bc) * sEw[sbase];
#pragma unroll
            for (int r = 1; r < 4; ++r) {
                const int d = sDst[sbase + r];
                const float v = (acc[mi][ni][r] + bc) * sEw[sbase + r];
                if (d == cur) av += v;
                else {
                    atomicAdd(agg + (size_t)cur * DH + col, av);
                    cur = d; av = v;
                }
            }
            atomicAdd(agg + (size_t)cur * DH + col, av);
        }
    }
}

// ---------------------------------------------------------------------------
// Kernel 3: node MLP + residual + LayerNorm. 32 nodes/block, 256 threads.
// ---------------------------------------------------------------------------
__global__ __launch_bounds__(256) void k_node(
    const float* __restrict__ h, const float* __restrict__ agg,
    const float* __restrict__ Wh1, const float* __restrict__ bh1,
    const float* __restrict__ Wh2, const float* __restrict__ bh2,
    const float* __restrict__ ln_g, const float* __restrict__ ln_b,
    float* __restrict__ out, int N)
{
    __shared__ float sU[2 * DH][36];
    __shared__ float sHid[DH][36];
    __shared__ float sW[16][DH];
    __shared__ float sMean[32], sRstd[32];
    const int tid = threadIdx.x;
    const int n0 = blockIdx.x * 32;

    {
        const int n = tid >> 3;
        const int c0 = (tid & 7) * 16;
        const int gn = n0 + n;
#pragma unroll
        for (int i = 0; i < 4; ++i) {
            float4 v = make_float4(0.f, 0.f, 0.f, 0.f);
            if (gn < N) v = *(const float4*)(h + (size_t)gn * DH + c0 + 4 * i);
            sU[c0 + 4 * i + 0][n] = v.x; sU[c0 + 4 * i + 1][n] = v.y;
            sU[c0 + 4 * i + 2][n] = v.z; sU[c0 + 4 * i + 3][n] = v.w;
        }
#pragma unroll
        for (int i = 0; i < 4; ++i) {
            float4 v = make_float4(0.f, 0.f, 0.f, 0.f);
            if (gn < N) v = *(const float4*)(agg + (size_t)gn * DH + c0 + 4 * i);
            sU[DH + c0 + 4 * i + 0][n] = v.x; sU[DH + c0 + 4 * i + 1][n] = v.y;
            sU[DH + c0 + 4 * i + 2][n] = v.z; sU[DH + c0 + 4 * i + 3][n] = v.w;
        }
    }

    const int ng = tid & 7;
    const int jg = tid >> 3;
    const int sr = tid >> 4;
    const int sc = (tid & 15) * 8;

    float acc[4][4];
#pragma unroll
    for (int i = 0; i < 4; ++i)
#pragma unroll
        for (int j = 0; j < 4; ++j) acc[i][j] = 0.f;

    float4 rw[2];
    rw[0] = *(const float4*)(Wh1 + (size_t)sr * DH + sc);
    rw[1] = *(const float4*)(Wh1 + (size_t)sr * DH + sc + 4);
    for (int t = 0; t < 16; ++t) {
        __syncthreads();
        *(float4*)&sW[sr][sc]     = rw[0];
        *(float4*)&sW[sr][sc + 4] = rw[1];
        __syncthreads();
        if (t < 15) {
            const int k0 = 16 * (t + 1);
            rw[0] = *(const float4*)(Wh1 + (size_t)(k0 + sr) * DH + sc);
            rw[1] = *(const float4*)(Wh1 + (size_t)(k0 + sr) * DH + sc + 4);
        }
#pragma unroll
        for (int kk = 0; kk < 16; ++kk) {
            const float4 a = *(const float4*)&sU[t * 16 + kk][ng * 4];
            const float4 b = *(const float4*)&sW[kk][jg * 4];
            const float av[4] = {a.x, a.y, a.z, a.w};
            const float bv[4] = {b.x, b.y, b.z, b.w};
#pragma unroll
            for (int i = 0; i < 4; ++i)
#pragma unroll
                for (int j = 0; j < 4; ++j)
                    acc[i][j] = fmaf(av[i], bv[j], acc[i][j]);
        }
    }
#pragma unroll
    for (int jj = 0; jj < 4; ++jj) {
        const float bb = bh1[jg * 4 + jj];
#pragma unroll
        for (int i = 0; i < 4; ++i)
            sHid[jg * 4 + jj][ng * 4 + i] = silu_f(acc[i][jj] + bb);
    }

    float acc2[4][4];
#pragma unroll
    for (int i = 0; i < 4; ++i)
#pragma unroll
        for (int j = 0; j < 4; ++j) acc2[i][j] = 0.f;

    rw[0] = *(const float4*)(Wh2 + (size_t)sr * DH + sc);
    rw[1] = *(const float4*)(Wh2 + (size_t)sr * DH + sc + 4);
    for (int t = 0; t < 8; ++t) {
        __syncthreads();
        *(float4*)&sW[sr][sc]     = rw[0];
        *(float4*)&sW[sr][sc + 4] = rw[1];
        __syncthreads();
        if (t < 7) {
            const int k0 = 16 * (t + 1);
            rw[0] = *(const float4*)(Wh2 + (size_t)(k0 + sr) * DH + sc);
            rw[1] = *(const float4*)(Wh2 + (size_t)(k0 + sr) * DH + sc + 4);
        }
#pragma unroll
        for (int kk = 0; kk < 16; ++kk) {
            const float4 a = *(const float4*)&sHid[t * 16 + kk][ng * 4];
            const float4 b = *(const float4*)&sW[kk][jg * 4];
            const float av[4] = {a.x, a.y, a.z, a.w};
            const float bv[4] = {b.x, b.y, b.z, b.w};
#pragma unroll
            for (int i = 0; i < 4; ++i)
#pragma unroll
                for (int j = 0; j < 4; ++j)
                    acc2[i][j] = fmaf(av[i], bv[j], acc2[i][j]);
        }
    }

#pragma unroll
    for (int jj = 0; jj < 4; ++jj) {
        const float bb = bh2[jg * 4 + jj];
#pragma unroll
        for (int i = 0; i < 4; ++i) {
            const int gn = n0 + ng * 4 + i;
            float hv = 0.f;
            if (gn < N) hv = h[(size_t)gn * DH + jg * 4 + jj];
            sU[jg * 4 + jj][ng * 4 + i] = acc2[i][jj] + bb + hv;
        }
    }
    __syncthreads();

    {
        const int n = tid >> 3, sub = tid & 7;
        float s1 = 0.f, s2 = 0.f;
#pragma unroll
        for (int i = 0; i < 16; ++i) {
            const float z = sU[sub + 8 * i][n];
            s1 += z; s2 += z * z;
        }
#pragma unroll
        for (int m = 1; m < 8; m <<= 1) {
            s1 += __shfl_xor(s1, m, 64);
            s2 += __shfl_xor(s2, m, 64);
        }
        if (sub == 0) {
            const float mean = s1 * (1.f / 128.f);
            const float var = s2 * (1.f / 128.f) - mean * mean;
            sMean[n] = mean;
            sRstd[n] = rsqrtf(var + 1e-5f);
        }
    }
    __syncthreads();
    {
        const int n = tid >> 3, c0 = (tid & 7) * 16;
        const int gn = n0 + n;
        if (gn < N) {
            const float mean = sMean[n], rstd = sRstd[n];
#pragma unroll
            for (int i = 0; i < 4; ++i) {
                const float4 g4 = *(const float4*)(ln_g + c0 + 4 * i);
                const float4 b4 = *(const float4*)(ln_b + c0 + 4 * i);
                float4 o;
                o.x = (sU[c0 + 4 * i + 0][n] - mean) * rstd * g4.x + b4.x;
                o.y = (sU[c0 + 4 * i + 1][n] - mean) * rstd * g4.y + b4.y;
                o.z = (sU[c0 + 4 * i + 2][n] - mean) * rstd * g4.z + b4.z;
                o.w = (sU[c0 + 4 * i + 3][n] - mean) * rstd * g4.w + b4.w;
                *(float4*)(out + (size_t)gn * DH + c0 + 4 * i) = o;
            }
        }
    }
}

extern "C" void kernel_launch(void* const* d_in, const int* in_sizes, int n_in,
                              void* d_out, int out_size, void* d_ws, size_t ws_size,
                              hipStream_t stream)
{
    (void)n_in; (void)out_size;
    const float* h   = (const float*)d_in[0];
    const float* x   = (const float*)d_in[1];
    const int*   ei  = (const int*)d_in[2];
    const float* ew  = (const float*)d_in[3];
    const float* Wm1 = (const float*)d_in[4];
    const float* bm1 = (const float*)d_in[5];
    const float* Wm2 = (const float*)d_in[6];
    const float* bm2 = (const float*)d_in[7];
    const float* Wh1 = (const float*)d_in[8];
    const float* bh1 = (const float*)d_in[9];
    const float* Wh2 = (const float*)d_in[10];
    const float* bh2 = (const float*)d_in[11];
    const float* lng = (const float*)d_in[12];
    const float* lnb = (const float*)d_in[13];
    float* out = (float*)d_out;

    const int N = in_sizes[0] / DH;
    const int E = in_sizes[3];

    float* agg = (float*)d_ws;
    float* A   = agg + (size_t)N * DH;
    float* B   = A + (size_t)N * DH;
    int* counts = (int*)(B + (size_t)N * DH);
    int* cursor = counts + N;
    int* perm   = cursor + N;
    int* flag   = perm + E;

    const size_t need = 3 * (size_t)N * DH * sizeof(float) + (size_t)(2 * N + E + 1) * sizeof(int);
    const int use_sort = (ws_size >= need) ? 1 : 0;
    if (!use_sort) flag = counts;  // minimal layout

    hipMemsetAsync(agg, 0, (size_t)N * DH * sizeof(float), stream);
    k_detect<<<1, 64, 0, stream>>>(ei, flag);
    if (use_sort) {
        hipMemsetAsync(counts, 0, (size_t)N * sizeof(int), stream);
        k_hist<<<(E + 255) / 256, 256, 0, stream>>>(ei, flag, counts, E);
        k_scan<<<1, 1024, 0, stream>>>(counts, cursor, N);
        k_scatter<<<(E + 255) / 256, 256, 0, stream>>>(ei, flag, cursor, perm, E);
    }
    k_precompute_ab<<<(N + 31) / 32, 256, 0, stream>>>(h, Wm1, bm1, A, B, N);
    k_edge<<<(E + EB - 1) / EB, 256, 0, stream>>>(x, ei, ew, Wm1, Wm2, bm2, A, B,
                                                  agg, flag, perm, use_sort, N, E);
    k_node<<<(N + 31) / 32, 256, 0, stream>>>(h, agg, Wh1, bh1, Wh2, bh2, lng, lnb, out, N);
}